// Round 6
// baseline (1005.247 us; speedup 1.0000x reference)
//
#include <hip/hip_runtime.h>

#define NBLK 256
#define NTHR 256

typedef __bf16 bf16x8 __attribute__((ext_vector_type(8)));
typedef float  f32x4  __attribute__((ext_vector_type(4)));

__device__ __forceinline__ unsigned short f2bf(float f) {
  unsigned int u = __float_as_uint(f);
  return (unsigned short)((u + 0x7fffu + ((u >> 16) & 1u)) >> 16);  // RNE
}

__device__ __forceinline__ bf16x8 asbf(uint4 u) {
  return __builtin_bit_cast(bf16x8, u);
}

__device__ __forceinline__ float sigf(float xv) { return 1.0f / (1.0f + __expf(-xv)); }

// ws layout (bytes):
//   OUTB  bf16 [2][32][1024]            parity ping-pong of cell input   131072
//   HBB   bf16 [2][2][32][1024]         [t-parity][layer] h for GEMM     262144
//   WBLK  bf16 [256][2][16][2048]       per-block weight slices        33554432
//   SSE   f32
//   BARC  int                           grid barrier counter (monotonic)
#define WS_OUTB 0
#define WS_HBB  131072
#define WS_WBLK 393216
#define WS_SSE  (393216 + 33554432)
#define WS_BARC (WS_SSE + 4)

// ---------------- prep: init activations + counters ----------------
__global__ void prep_kernel(const float* __restrict__ x, const float* __restrict__ h0,
                            unsigned char* __restrict__ ws)
{
  unsigned short* outb = (unsigned short*)(ws + WS_OUTB);
  unsigned short* hbb  = (unsigned short*)(ws + WS_HBB);
  int gid = blockIdx.x * blockDim.x + threadIdx.x;
  int stride = gridDim.x * blockDim.x;
  for (int i = gid; i < 32768; i += stride) outb[i] = f2bf(x[i]);   // parity 0 = x
  for (int i = gid; i < 65536; i += stride) hbb[i]  = f2bf(h0[i]);  // t-parity 0, both layers
  if (gid == 0) {
    *(float*)(ws + WS_SSE) = 0.0f;
    *(int*)(ws + WS_BARC) = 0;
  }
}

// ---------------- persistent kernel ----------------
// 256 blocks x 256 threads. Block owns 4 H-cols (j0=bid*4) x 4 gates x both layers.
// vcol = gate*4 + hc packs the 16 MFMA B-columns. Waves = 4 K-quarters (512 each).
// B reloaded per cell from L2 (breg[16] = 64 VGPRs, literal-indexed). A read
// directly from global (L2 broadcast). LDS = gate partials only.
__global__ void __launch_bounds__(NTHR, 1)
persist_kernel(const float* __restrict__ h0, const float* __restrict__ c0,
               const float* __restrict__ hmask, const float* __restrict__ cmask,
               const float* __restrict__ labels,
               const float* __restrict__ Wih, const float* __restrict__ Whh,
               const float* __restrict__ bih, const float* __restrict__ bhh,
               float* __restrict__ out, unsigned char* __restrict__ ws)
{
  const int tid = threadIdx.x;
  const int bid = blockIdx.x;
  const int j0  = bid * 4;           // this block's 4 H-columns

  unsigned short* outb = (unsigned short*)(ws + WS_OUTB);
  unsigned short* hbb  = (unsigned short*)(ws + WS_HBB);
  unsigned short* Wblk = (unsigned short*)(ws + WS_WBLK);
  float*          sse  = (float*)(ws + WS_SSE);
  int*            barc = (int*)(ws + WS_BARC);

  __shared__ float Ps[4 * 544];      // [kq][m*17 + vcol], 8704 B

  const int lane = tid & 63;
  const int kq   = tid >> 6;         // wave = K-quarter
  const int q    = lane >> 4;
  const int m0   = lane & 15;

  // ---- one-time: convert this block's weight slice fp32 -> bf16 into Wblk ----
  // slice: [l][vcol=g*4+hc][2048 K] ; K-concat [Wih | Whh]
  for (int idx = tid; idx < 16384; idx += NTHR) {
    int l  = idx >> 13;
    int vc = (idx >> 9) & 15;
    int k4 = idx & 511;
    int g  = vc >> 2, hc = vc & 3;
    size_t rowbase = (size_t)(l * 4096 + g * 1024 + j0 + hc) * 1024;
    const float* src = (k4 < 256) ? (Wih + rowbase + (size_t)k4 * 4)
                                  : (Whh + rowbase + (size_t)(k4 - 256) * 4);
    float4 v = *(const float4*)src;
    ushort4 o;
    o.x = f2bf(v.x); o.y = f2bf(v.y); o.z = f2bf(v.z); o.w = f2bf(v.w);
    *(ushort4*)(Wblk + ((size_t)(bid * 2 + l) * 16 + vc) * 2048 + (size_t)k4 * 4) = o;
  }

  // ---- per-thread persistent state: tid<128 owns (m=tid>>2, hc=tid&3), both layers ----
  const int pm = tid >> 2;
  const int hc = tid & 3;
  const int jg = j0 + hc;
  float hs0 = 0.f, cs0 = 0.f, hs1 = 0.f, cs1 = 0.f;
  float4 b0 = {0,0,0,0}, b1 = {0,0,0,0};
  if (tid < 128) {
    hs0 = h0[(0 * 32 + pm) * 1024 + jg];  cs0 = c0[(0 * 32 + pm) * 1024 + jg];
    hs1 = h0[(1 * 32 + pm) * 1024 + jg];  cs1 = c0[(1 * 32 + pm) * 1024 + jg];
    b0.x = bih[0 * 1024 + jg] + bhh[0 * 1024 + jg];
    b0.y = bih[1 * 1024 + jg] + bhh[1 * 1024 + jg];
    b0.z = bih[2 * 1024 + jg] + bhh[2 * 1024 + jg];
    b0.w = bih[3 * 1024 + jg] + bhh[3 * 1024 + jg];
    b1.x = bih[4096 + 0 * 1024 + jg] + bhh[4096 + 0 * 1024 + jg];
    b1.y = bih[4096 + 1 * 1024 + jg] + bhh[4096 + 1 * 1024 + jg];
    b1.z = bih[4096 + 2 * 1024 + jg] + bhh[4096 + 2 * 1024 + jg];
    b1.w = bih[4096 + 3 * 1024 + jg] + bhh[4096 + 3 * 1024 + jg];
  }
  float local_sse = 0.0f;

  for (int ci = 0; ci < 32; ++ci) {
    const int t = ci >> 1;
    const int l = ci & 1;

    // ---- B prefetch: this wave's 16 vcols x 512 K from L2 (literal indices) ----
    const unsigned short* wb =
        Wblk + ((size_t)(bid * 2 + l) * 16 + m0) * 2048 + kq * 512 + q * 8;
    uint4 breg[16];
#pragma unroll
    for (int ks = 0; ks < 16; ++ks) breg[ks] = *(const uint4*)(wb + ks * 32);

    // ---- early pointwise operand loads (HBM latency hidden by GEMM) ----
    float hmv = 0.f, cmv = 0.f, lbv = 0.f;
    if (tid < 128) {
      int mbase = ((t * 2 + l) * 32 + pm) * 1024 + jg;
      hmv = hmask[mbase];
      cmv = cmask[mbase];
      if (l == 1) lbv = labels[(pm * 16 + t) * 1024 + jg];
    }

    // ---- A fragments straight from global (L2-broadcast), MFMA over K=512 ----
    const unsigned short* outc = outb + l * 32768;
    const unsigned short* hbc  = hbb + ((t & 1) * 2 + l) * 32768;
    const unsigned short* asrc = (kq < 2) ? (outc + kq * 512) : (hbc + (kq - 2) * 512);
    f32x4 acc0 = {0.f,0.f,0.f,0.f}, acc1 = {0.f,0.f,0.f,0.f};
#pragma unroll
    for (int ks = 0; ks < 16; ++ks) {
      int koff = ks * 32 + q * 8;
      uint4 a0 = *(const uint4*)(asrc + m0 * 1024 + koff);
      uint4 a1 = *(const uint4*)(asrc + (m0 + 16) * 1024 + koff);
      acc0 = __builtin_amdgcn_mfma_f32_16x16x32_bf16(asbf(a0), asbf(breg[ks]), acc0, 0, 0, 0);
      acc1 = __builtin_amdgcn_mfma_f32_16x16x32_bf16(asbf(a1), asbf(breg[ks]), acc1, 0, 0, 0);
    }
    // ---- partials to LDS: [kq][m(stride17)][vcol] ----
#pragma unroll
    for (int i = 0; i < 4; ++i) {
      int r0 = q * 4 + i;              // C/D: row = quad*4+reg, col = lane&15 = vcol
      Ps[kq * 544 + r0 * 17 + m0]        = acc0[i];
      Ps[kq * 544 + (r0 + 16) * 17 + m0] = acc1[i];
    }
    __syncthreads();

    // ---- pointwise: tid<128, one (m, hc) each ----
    if (tid < 128) {
      float gsum[4];
#pragma unroll
      for (int g = 0; g < 4; ++g)
        gsum[g] = Ps[0 * 544 + pm * 17 + g * 4 + hc] + Ps[1 * 544 + pm * 17 + g * 4 + hc]
                + Ps[2 * 544 + pm * 17 + g * 4 + hc] + Ps[3 * 544 + pm * 17 + g * 4 + hc];
      float gi = gsum[0] + (l ? b1.x : b0.x);
      float gf = gsum[1] + (l ? b1.y : b0.y);
      float gg = gsum[2] + (l ? b1.z : b0.z);
      float go = gsum[3] + (l ? b1.w : b0.w);
      float ii = sigf(gi), ff = sigf(gf), oo = sigf(go);
      float gt = tanhf(gg);
      float cprev = l ? cs1 : cs0;
      float hprev = l ? hs1 : hs0;
      float ccand = ff * cprev + ii * gt;
      float hcand = oo * tanhf(ccand);
      float hnew = hmv * hprev + (1.0f - hmv) * hcand;
      float cnew = cmv * cprev + (1.0f - cmv) * ccand;
      if (l) { cs1 = cnew; hs1 = hnew; } else { cs0 = cnew; hs0 = hnew; }
      unsigned short ub = f2bf(hnew);
      outb[(l ^ 1) * 32768 + pm * 1024 + jg] = ub;                 // next cell's input
      hbb[(((t + 1) & 1) * 2 + l) * 32768 + pm * 1024 + jg] = ub;  // next t, same layer
      if (l == 1) {
        out[(pm * 16 + t) * 1024 + jg] = hnew;                     // ret[b][t][h]
        float d = hnew - lbv;
        local_sse += d * d;
      }
    }

    // ---- grid barrier (monotonic counter, agent scope; proven R4/R5) ----
    __syncthreads();
    if (tid == 0) {
      __threadfence();
      __hip_atomic_fetch_add(barc, 1, __ATOMIC_RELAXED, __HIP_MEMORY_SCOPE_AGENT);
      const int tgt = NBLK * (ci + 1);
      while (__hip_atomic_load(barc, __ATOMIC_RELAXED, __HIP_MEMORY_SCOPE_AGENT) < tgt)
        __builtin_amdgcn_s_sleep(1);
      __threadfence();
    }
    __syncthreads();
  }

  // ---------------- loss ----------------
  if (tid < 128) {
    float s = local_sse;
#pragma unroll
    for (int off = 32; off > 0; off >>= 1) s += __shfl_down(s, off);
    if (lane == 0) atomicAdd(sse, s);
  }
  __syncthreads();
  if (tid == 0) {
    __threadfence();
    __hip_atomic_fetch_add(barc, 1, __ATOMIC_RELAXED, __HIP_MEMORY_SCOPE_AGENT);
    while (__hip_atomic_load(barc, __ATOMIC_RELAXED, __HIP_MEMORY_SCOPE_AGENT) < NBLK * 33)
      __builtin_amdgcn_s_sleep(1);
    __threadfence();
  }
  __syncthreads();
  if (bid == 0 && tid == 0)
    out[524288] = __hip_atomic_load(sse, __ATOMIC_RELAXED, __HIP_MEMORY_SCOPE_AGENT)
                  * (1.0f / 524288.0f);
}

extern "C" void kernel_launch(void* const* d_in, const int* in_sizes, int n_in,
                              void* d_out, int out_size, void* d_ws, size_t ws_size,
                              hipStream_t stream) {
  (void)in_sizes; (void)n_in; (void)out_size; (void)ws_size;
  const float* x   = (const float*)d_in[0];
  const float* h0  = (const float*)d_in[1];
  const float* c0  = (const float*)d_in[2];
  const float* hm  = (const float*)d_in[3];
  const float* cm  = (const float*)d_in[4];
  const float* lb  = (const float*)d_in[5];
  const float* wih = (const float*)d_in[6];
  const float* whh = (const float*)d_in[7];
  const float* bi  = (const float*)d_in[8];
  const float* bh  = (const float*)d_in[9];
  float* out = (float*)d_out;
  unsigned char* ws = (unsigned char*)d_ws;

  prep_kernel<<<dim3(256), dim3(256), 0, stream>>>(x, h0, ws);
  persist_kernel<<<dim3(NBLK), dim3(NTHR), 0, stream>>>(h0, c0, hm, cm, lb,
                                                        wih, whh, bi, bh, out, ws);
}

// Round 7
// 904.777 us; speedup vs baseline: 1.1110x; 1.1110x over previous
//
#include <hip/hip_runtime.h>

#define NBLK 256
#define NTHR 256
#define DYN_LDS 131072   // [2][4][16][4][16] uint4 = bf16 weights, fragment-ordered

typedef __bf16 bf16x8 __attribute__((ext_vector_type(8)));
typedef float  f32x4  __attribute__((ext_vector_type(4)));

__device__ __forceinline__ unsigned short f2bf(float f) {
  unsigned int u = __float_as_uint(f);
  return (unsigned short)((u + 0x7fffu + ((u >> 16) & 1u)) >> 16);  // RNE
}

__device__ __forceinline__ bf16x8 asbf(uint4 u) {
  return __builtin_bit_cast(bf16x8, u);
}

__device__ __forceinline__ float sigf(float xv) { return 1.0f / (1.0f + __expf(-xv)); }

// ws layout (bytes):
//   OUTB  bf16 [2][32][1024]     parity ping-pong of cell input   131072
//   HBB   bf16 [2][2][32][1024]  [t-parity][layer] h for GEMM     262144
//   SSE   f32
//   BARC  int                    grid barrier counter (monotonic)
#define WS_OUTB 0
#define WS_HBB  131072
#define WS_SSE  (131072 + 262144)
#define WS_BARC (WS_SSE + 4)

// ---------------- prep: init activations + counters ----------------
__global__ void prep_kernel(const float* __restrict__ x, const float* __restrict__ h0,
                            unsigned char* __restrict__ ws)
{
  unsigned short* outb = (unsigned short*)(ws + WS_OUTB);
  unsigned short* hbb  = (unsigned short*)(ws + WS_HBB);
  int gid = blockIdx.x * blockDim.x + threadIdx.x;
  int stride = gridDim.x * blockDim.x;
  for (int i = gid; i < 32768; i += stride) outb[i] = f2bf(x[i]);   // parity 0 = x
  for (int i = gid; i < 65536; i += stride) hbb[i]  = f2bf(h0[i]);  // t-parity 0, both layers
  if (gid == 0) {
    *(float*)(ws + WS_SSE) = 0.0f;
    *(int*)(ws + WS_BARC) = 0;
  }
}

// ---------------- persistent kernel: weights resident in LDS ----------------
// 256 blocks x 256 threads, 1 block/CU (LDS-bound). Block owns 4 H-cols
// (j0=bid*4) x 4 gates x both layers; vcol = gate*4+hc packs 16 MFMA B-cols.
// Waves = 4 K-quarters. B lives in LDS, fragment-ordered:
//   Ws[ ((((l*4+kq)*16+ks)*4+q)*16+vcol) * 8 shorts ]   (one uint4 per lane)
// A fragments read straight from ws (L2 broadcast). Gate partials in static LDS.
__global__ void __launch_bounds__(NTHR, 1)
persist_kernel(const float* __restrict__ h0, const float* __restrict__ c0,
               const float* __restrict__ hmask, const float* __restrict__ cmask,
               const float* __restrict__ labels,
               const float* __restrict__ Wih, const float* __restrict__ Whh,
               const float* __restrict__ bih, const float* __restrict__ bhh,
               float* __restrict__ out, unsigned char* __restrict__ ws)
{
  extern __shared__ __align__(16) unsigned short Ws[];   // 131072 B dynamic
  __shared__ float Ps[4 * 544];                          // [kq][m*17 + vcol], 8704 B

  const int tid = threadIdx.x;
  const int bid = blockIdx.x;
  const int j0  = bid * 4;

  unsigned short* outb = (unsigned short*)(ws + WS_OUTB);
  unsigned short* hbb  = (unsigned short*)(ws + WS_HBB);
  float*          sse  = (float*)(ws + WS_SSE);
  int*            barc = (int*)(ws + WS_BARC);

  const int lane = tid & 63;
  const int kq   = tid >> 6;         // wave = K-quarter
  const int q    = lane >> 4;
  const int m0   = lane & 15;

  // ---- one-time: fp32 weights -> bf16 fragments in LDS (read HBM once) ----
  // idx over (l, vcol, k8): 2*16*256 = 8192 iters / 256 thr = 32 each
  for (int idx = tid; idx < 8192; idx += NTHR) {
    int l    = idx >> 12;
    int rem  = idx & 4095;
    int vc   = rem >> 8;
    int k8   = rem & 255;
    int k    = k8 * 8;
    int kqw  = k >> 9, ksw = (k >> 5) & 15, qw = (k >> 3) & 3;
    int g    = vc >> 2, hc = vc & 3;
    size_t rowbase = (size_t)(l * 4096 + g * 1024 + j0 + hc) * 1024;
    const float* src = (k < 1024) ? (Wih + rowbase + k) : (Whh + rowbase + (k - 1024));
    float4 f0 = *(const float4*)src;
    float4 f1 = *(const float4*)(src + 4);
    uint4 u;
    u.x = (unsigned)f2bf(f0.x) | ((unsigned)f2bf(f0.y) << 16);
    u.y = (unsigned)f2bf(f0.z) | ((unsigned)f2bf(f0.w) << 16);
    u.z = (unsigned)f2bf(f1.x) | ((unsigned)f2bf(f1.y) << 16);
    u.w = (unsigned)f2bf(f1.z) | ((unsigned)f2bf(f1.w) << 16);
    *(uint4*)&Ws[(size_t)((((l * 4 + kqw) * 16 + ksw) * 4 + qw) * 16 + vc) * 8] = u;
  }

  // ---- per-thread persistent state: tid<128 owns (m=tid>>2, hc=tid&3), both layers ----
  const int pm = tid >> 2;
  const int hc = tid & 3;
  const int jg = j0 + hc;
  float hs0 = 0.f, cs0 = 0.f, hs1 = 0.f, cs1 = 0.f;
  float4 b0 = {0,0,0,0}, b1 = {0,0,0,0};
  if (tid < 128) {
    hs0 = h0[(0 * 32 + pm) * 1024 + jg];  cs0 = c0[(0 * 32 + pm) * 1024 + jg];
    hs1 = h0[(1 * 32 + pm) * 1024 + jg];  cs1 = c0[(1 * 32 + pm) * 1024 + jg];
    b0.x = bih[0 * 1024 + jg] + bhh[0 * 1024 + jg];
    b0.y = bih[1 * 1024 + jg] + bhh[1 * 1024 + jg];
    b0.z = bih[2 * 1024 + jg] + bhh[2 * 1024 + jg];
    b0.w = bih[3 * 1024 + jg] + bhh[3 * 1024 + jg];
    b1.x = bih[4096 + 0 * 1024 + jg] + bhh[4096 + 0 * 1024 + jg];
    b1.y = bih[4096 + 1 * 1024 + jg] + bhh[4096 + 1 * 1024 + jg];
    b1.z = bih[4096 + 2 * 1024 + jg] + bhh[4096 + 2 * 1024 + jg];
    b1.w = bih[4096 + 3 * 1024 + jg] + bhh[4096 + 3 * 1024 + jg];
  }
  float local_sse = 0.0f;

  __syncthreads();                   // weights staged before first GEMM

  for (int ci = 0; ci < 32; ++ci) {
    const int t = ci >> 1;
    const int l = ci & 1;

    // ---- early pointwise operand loads (latency hidden by GEMM) ----
    float hmv = 0.f, cmv = 0.f, lbv = 0.f;
    if (tid < 128) {
      int mbase = ((t * 2 + l) * 32 + pm) * 1024 + jg;
      hmv = hmask[mbase];
      cmv = cmask[mbase];
      if (l == 1) lbv = labels[(pm * 16 + t) * 1024 + jg];
    }

    // ---- GEMM over K=512: A from global (L2), B from LDS ----
    const unsigned short* outc = outb + l * 32768;
    const unsigned short* hbc  = hbb + ((t & 1) * 2 + l) * 32768;
    const unsigned short* asrc = (kq < 2) ? (outc + kq * 512) : (hbc + (kq - 2) * 512);
    const unsigned short* wfrag = Ws + (size_t)(((l * 4 + kq) * 16) * 4 + q) * 16 * 8 + lane * 0;
    f32x4 acc0 = {0.f,0.f,0.f,0.f}, acc1 = {0.f,0.f,0.f,0.f};
#pragma unroll
    for (int ks = 0; ks < 16; ++ks) {
      int koff = ks * 32 + q * 8;
      uint4 a0 = *(const uint4*)(asrc + m0 * 1024 + koff);
      uint4 a1 = *(const uint4*)(asrc + (m0 + 16) * 1024 + koff);
      uint4 bfr = *(const uint4*)&Ws[(size_t)((((l * 4 + kq) * 16 + ks) * 4 + q) * 16 + m0) * 8];
      acc0 = __builtin_amdgcn_mfma_f32_16x16x32_bf16(asbf(a0), asbf(bfr), acc0, 0, 0, 0);
      acc1 = __builtin_amdgcn_mfma_f32_16x16x32_bf16(asbf(a1), asbf(bfr), acc1, 0, 0, 0);
    }
    (void)wfrag;
    // ---- partials to LDS: [kq][m(stride17)][vcol] ----
#pragma unroll
    for (int i = 0; i < 4; ++i) {
      int r0 = q * 4 + i;              // C/D: row = quad*4+reg, col = lane&15 = vcol
      Ps[kq * 544 + r0 * 17 + m0]        = acc0[i];
      Ps[kq * 544 + (r0 + 16) * 17 + m0] = acc1[i];
    }
    __syncthreads();

    // ---- pointwise: tid<128, one (m, hc) each ----
    if (tid < 128) {
      float gsum[4];
#pragma unroll
      for (int g = 0; g < 4; ++g)
        gsum[g] = Ps[0 * 544 + pm * 17 + g * 4 + hc] + Ps[1 * 544 + pm * 17 + g * 4 + hc]
                + Ps[2 * 544 + pm * 17 + g * 4 + hc] + Ps[3 * 544 + pm * 17 + g * 4 + hc];
      float gi = gsum[0] + (l ? b1.x : b0.x);
      float gf = gsum[1] + (l ? b1.y : b0.y);
      float gg = gsum[2] + (l ? b1.z : b0.z);
      float go = gsum[3] + (l ? b1.w : b0.w);
      float ii = sigf(gi), ff = sigf(gf), oo = sigf(go);
      float gt = tanhf(gg);
      float cprev = l ? cs1 : cs0;
      float hprev = l ? hs1 : hs0;
      float ccand = ff * cprev + ii * gt;
      float hcand = oo * tanhf(ccand);
      float hnew = hmv * hprev + (1.0f - hmv) * hcand;
      float cnew = cmv * cprev + (1.0f - cmv) * ccand;
      if (l) { cs1 = cnew; hs1 = hnew; } else { cs0 = cnew; hs0 = hnew; }
      unsigned short ub = f2bf(hnew);
      outb[(l ^ 1) * 32768 + pm * 1024 + jg] = ub;                 // next cell's input
      hbb[(((t + 1) & 1) * 2 + l) * 32768 + pm * 1024 + jg] = ub;  // next t, same layer
      if (l == 1) {
        out[(pm * 16 + t) * 1024 + jg] = hnew;                     // ret[b][t][h]
        float d = hnew - lbv;
        local_sse += d * d;
      }
    }

    // ---- grid barrier (monotonic counter, agent scope; proven R4-R6) ----
    __syncthreads();
    if (tid == 0) {
      __threadfence();
      __hip_atomic_fetch_add(barc, 1, __ATOMIC_RELAXED, __HIP_MEMORY_SCOPE_AGENT);
      const int tgt = NBLK * (ci + 1);
      while (__hip_atomic_load(barc, __ATOMIC_RELAXED, __HIP_MEMORY_SCOPE_AGENT) < tgt)
        __builtin_amdgcn_s_sleep(1);
      __threadfence();
    }
    __syncthreads();
  }

  // ---------------- loss ----------------
  if (tid < 128) {
    float s = local_sse;
#pragma unroll
    for (int off = 32; off > 0; off >>= 1) s += __shfl_down(s, off);
    if (lane == 0) atomicAdd(sse, s);
  }
  __syncthreads();
  if (tid == 0) {
    __threadfence();
    __hip_atomic_fetch_add(barc, 1, __ATOMIC_RELAXED, __HIP_MEMORY_SCOPE_AGENT);
    while (__hip_atomic_load(barc, __ATOMIC_RELAXED, __HIP_MEMORY_SCOPE_AGENT) < NBLK * 33)
      __builtin_amdgcn_s_sleep(1);
    __threadfence();
  }
  __syncthreads();
  if (bid == 0 && tid == 0)
    out[524288] = __hip_atomic_load(sse, __ATOMIC_RELAXED, __HIP_MEMORY_SCOPE_AGENT)
                  * (1.0f / 524288.0f);
}

extern "C" void kernel_launch(void* const* d_in, const int* in_sizes, int n_in,
                              void* d_out, int out_size, void* d_ws, size_t ws_size,
                              hipStream_t stream) {
  (void)in_sizes; (void)n_in; (void)out_size; (void)ws_size;
  const float* x   = (const float*)d_in[0];
  const float* h0  = (const float*)d_in[1];
  const float* c0  = (const float*)d_in[2];
  const float* hm  = (const float*)d_in[3];
  const float* cm  = (const float*)d_in[4];
  const float* lb  = (const float*)d_in[5];
  const float* wih = (const float*)d_in[6];
  const float* whh = (const float*)d_in[7];
  const float* bi  = (const float*)d_in[8];
  const float* bh  = (const float*)d_in[9];
  float* out = (float*)d_out;
  unsigned char* ws = (unsigned char*)d_ws;

  // allow 128 KB dynamic LDS (idempotent; host-side attr set, not a stream op)
  static bool attr_done = false;
  if (!attr_done) {
    hipFuncSetAttribute((const void*)persist_kernel,
                        hipFuncAttributeMaxDynamicSharedMemorySize, DYN_LDS);
    attr_done = true;
  }

  prep_kernel<<<dim3(256), dim3(256), 0, stream>>>(x, h0, ws);
  persist_kernel<<<dim3(NBLK), dim3(NTHR), DYN_LDS, stream>>>(h0, c0, hm, cm, lb,
                                                              wih, whh, bi, bh, out, ws);
}

// Round 8
// 778.954 us; speedup vs baseline: 1.2905x; 1.1615x over previous
//
#include <hip/hip_runtime.h>

#define NBLK 256
#define NTHR 1024
#define DYN_LDS 131072   // bf16 weights: [l][kq8][ks8][q4][vcol16] x uint4

typedef __bf16 bf16x8 __attribute__((ext_vector_type(8)));
typedef float  f32x4  __attribute__((ext_vector_type(4)));

__device__ __forceinline__ unsigned short f2bf(float f) {
  unsigned int u = __float_as_uint(f);
  return (unsigned short)((u + 0x7fffu + ((u >> 16) & 1u)) >> 16);  // RNE
}

__device__ __forceinline__ bf16x8 asbf(uint4 u) {
  return __builtin_bit_cast(bf16x8, u);
}

__device__ __forceinline__ float sigf(float xv) { return 1.0f / (1.0f + __expf(-xv)); }

// ws layout (bytes):
//   OUTB  bf16 [2][32][1024]     parity ping-pong of cell input   131072
//   HBB   bf16 [2][2][32][1024]  [t-parity][layer] h for GEMM     262144
//   SSE   f32
//   GCNT  int [8] spaced 64B     group barrier counters            512
//   ROOT  int                    root barrier counter
#define WS_OUTB 0
#define WS_HBB  131072
#define WS_SSE  (131072 + 262144)
#define WS_GCNT (WS_SSE + 64)
#define WS_ROOT (WS_GCNT + 512)

// ---------------- prep: init activations + counters ----------------
__global__ void prep_kernel(const float* __restrict__ x, const float* __restrict__ h0,
                            unsigned char* __restrict__ ws)
{
  unsigned short* outb = (unsigned short*)(ws + WS_OUTB);
  unsigned short* hbb  = (unsigned short*)(ws + WS_HBB);
  int gid = blockIdx.x * blockDim.x + threadIdx.x;
  int stride = gridDim.x * blockDim.x;
  for (int i = gid; i < 32768; i += stride) outb[i] = f2bf(x[i]);   // parity 0 = x
  for (int i = gid; i < 65536; i += stride) hbb[i]  = f2bf(h0[i]);  // t-parity 0, both layers
  if (gid == 0) *(float*)(ws + WS_SSE) = 0.0f;
  if (gid < 8)  *(int*)(ws + WS_GCNT + gid * 64) = 0;
  if (gid == 0) *(int*)(ws + WS_ROOT) = 0;
}

// ---------------- persistent kernel: weights in LDS, 16 waves/block ----------------
// 256 blocks x 1024 threads, 1 block/CU (LDS-bound), 4 waves/SIMD.
// Block owns 4 H-cols (j0=bid*4) x 4 gates x both layers; vcol = gate*4+hc.
// Wave = (kq in [0,8) K-slice of 256, mh in [0,2) row half). Per cell per wave:
// 8 A-loads up-front (global, L2/MALL) + 8 ds_read_b128 + 8 MFMA.
__global__ void __launch_bounds__(NTHR, 4)
persist_kernel(const float* __restrict__ h0, const float* __restrict__ c0,
               const float* __restrict__ hmask, const float* __restrict__ cmask,
               const float* __restrict__ labels,
               const float* __restrict__ Wih, const float* __restrict__ Whh,
               const float* __restrict__ bih, const float* __restrict__ bhh,
               float* __restrict__ out, unsigned char* __restrict__ ws)
{
  extern __shared__ __align__(16) unsigned short Ws[];   // 131072 B dynamic
  __shared__ float Ps[8 * 544];                          // [kq][m*17 + vcol], 17408 B

  const int tid = threadIdx.x;
  const int bid = blockIdx.x;
  const int j0  = bid * 4;

  unsigned short* outb = (unsigned short*)(ws + WS_OUTB);
  unsigned short* hbb  = (unsigned short*)(ws + WS_HBB);
  float*          sse  = (float*)(ws + WS_SSE);
  int*            gcnt = (int*)(ws + WS_GCNT + (bid & 7) * 64);
  int*            root = (int*)(ws + WS_ROOT);

  const int lane = tid & 63;
  const int w    = tid >> 6;         // 0..15
  const int kq   = w & 7;            // K-slice of 256
  const int mh   = w >> 3;           // row half
  const int q    = lane >> 4;
  const int m0   = lane & 15;

  // ---- one-time: fp32 weights -> bf16 fragments in LDS (read HBM once) ----
  for (int idx = tid; idx < 8192; idx += NTHR) {
    int l    = idx >> 12;
    int rem  = idx & 4095;
    int vc   = rem >> 8;
    int k8   = rem & 255;
    int k    = k8 * 8;
    int kqw  = k >> 8, ksw = (k >> 5) & 7, qw = (k >> 3) & 3;
    int g    = vc >> 2, hcv = vc & 3;
    size_t rowbase = (size_t)(l * 4096 + g * 1024 + j0 + hcv) * 1024;
    const float* src = (k < 1024) ? (Wih + rowbase + k) : (Whh + rowbase + (k - 1024));
    float4 f0 = *(const float4*)src;
    float4 f1 = *(const float4*)(src + 4);
    uint4 u;
    u.x = (unsigned)f2bf(f0.x) | ((unsigned)f2bf(f0.y) << 16);
    u.y = (unsigned)f2bf(f0.z) | ((unsigned)f2bf(f0.w) << 16);
    u.z = (unsigned)f2bf(f1.x) | ((unsigned)f2bf(f1.y) << 16);
    u.w = (unsigned)f2bf(f1.z) | ((unsigned)f2bf(f1.w) << 16);
    *(uint4*)&Ws[(size_t)((((l * 8 + kqw) * 8 + ksw) * 4 + qw) * 16 + vc) * 8] = u;
  }

  // ---- per-thread persistent state: tid<128 owns (m=tid>>2, hc=tid&3), both layers ----
  const int pm = tid >> 2;
  const int hc = tid & 3;
  const int jg = j0 + hc;
  float hs0 = 0.f, cs0 = 0.f, hs1 = 0.f, cs1 = 0.f;
  float4 b0 = {0,0,0,0}, b1 = {0,0,0,0};
  if (tid < 128) {
    hs0 = h0[(0 * 32 + pm) * 1024 + jg];  cs0 = c0[(0 * 32 + pm) * 1024 + jg];
    hs1 = h0[(1 * 32 + pm) * 1024 + jg];  cs1 = c0[(1 * 32 + pm) * 1024 + jg];
    b0.x = bih[0 * 1024 + jg] + bhh[0 * 1024 + jg];
    b0.y = bih[1 * 1024 + jg] + bhh[1 * 1024 + jg];
    b0.z = bih[2 * 1024 + jg] + bhh[2 * 1024 + jg];
    b0.w = bih[3 * 1024 + jg] + bhh[3 * 1024 + jg];
    b1.x = bih[4096 + 0 * 1024 + jg] + bhh[4096 + 0 * 1024 + jg];
    b1.y = bih[4096 + 1 * 1024 + jg] + bhh[4096 + 1 * 1024 + jg];
    b1.z = bih[4096 + 2 * 1024 + jg] + bhh[4096 + 2 * 1024 + jg];
    b1.w = bih[4096 + 3 * 1024 + jg] + bhh[4096 + 3 * 1024 + jg];
  }
  float local_sse = 0.0f;

  __syncthreads();                   // weights staged before first GEMM

  for (int ci = 0; ci < 32; ++ci) {
    const int t = ci >> 1;
    const int l = ci & 1;

    // ---- A-loads issued up-front: 8 independent uint4 per lane ----
    const unsigned short* outc = outb + l * 32768;
    const unsigned short* hbc  = hbb + ((t & 1) * 2 + l) * 32768;
    const unsigned short* asrc = (kq < 4) ? (outc + kq * 256) : (hbc + (kq - 4) * 256);
    const unsigned short* arow = asrc + (mh * 16 + m0) * 1024 + q * 8;
    uint4 areg[8];
#pragma unroll
    for (int ks = 0; ks < 8; ++ks) areg[ks] = *(const uint4*)(arow + ks * 32);

    // ---- early pointwise operand loads (latency hidden by GEMM) ----
    float hmv = 0.f, cmv = 0.f, lbv = 0.f;
    if (tid < 128) {
      int mbase = ((t * 2 + l) * 32 + pm) * 1024 + jg;
      hmv = hmask[mbase];
      cmv = cmask[mbase];
      if (l == 1) lbv = labels[(pm * 16 + t) * 1024 + jg];
    }

    // ---- MFMA over this wave's K=256 ----
    f32x4 acc = {0.f,0.f,0.f,0.f};
#pragma unroll
    for (int ks = 0; ks < 8; ++ks) {
      uint4 bfr = *(const uint4*)&Ws[(size_t)((((l * 8 + kq) * 8 + ks) * 4 + q) * 16 + m0) * 8];
      acc = __builtin_amdgcn_mfma_f32_16x16x32_bf16(asbf(areg[ks]), asbf(bfr), acc, 0, 0, 0);
    }
    // ---- partials to LDS: [kq][m(stride17)][vcol] ----
#pragma unroll
    for (int i = 0; i < 4; ++i) {
      int r = mh * 16 + q * 4 + i;     // C/D: row = quad*4+reg (A rows mh*16+..), col = vcol
      Ps[kq * 544 + r * 17 + m0] = acc[i];
    }
    __syncthreads();

    // ---- pointwise: tid<128, one (m, hc) each ----
    if (tid < 128) {
      float gsum[4];
#pragma unroll
      for (int g = 0; g < 4; ++g) {
        float s = 0.f;
#pragma unroll
        for (int k2 = 0; k2 < 8; ++k2) s += Ps[k2 * 544 + pm * 17 + g * 4 + hc];
        gsum[g] = s;
      }
      float gi = gsum[0] + (l ? b1.x : b0.x);
      float gf = gsum[1] + (l ? b1.y : b0.y);
      float gg = gsum[2] + (l ? b1.z : b0.z);
      float go = gsum[3] + (l ? b1.w : b0.w);
      float ii = sigf(gi), ff = sigf(gf), oo = sigf(go);
      float gt = tanhf(gg);
      float cprev = l ? cs1 : cs0;
      float hprev = l ? hs1 : hs0;
      float ccand = ff * cprev + ii * gt;
      float hcand = oo * tanhf(ccand);
      float hnew = hmv * hprev + (1.0f - hmv) * hcand;
      float cnew = cmv * cprev + (1.0f - cmv) * ccand;
      if (l) { cs1 = cnew; hs1 = hnew; } else { cs0 = cnew; hs0 = hnew; }
      unsigned short ub = f2bf(hnew);
      outb[(l ^ 1) * 32768 + pm * 1024 + jg] = ub;                 // next cell's input
      hbb[(((t + 1) & 1) * 2 + l) * 32768 + pm * 1024 + jg] = ub;  // next t, same layer
      if (l == 1) {
        out[(pm * 16 + t) * 1024 + jg] = hnew;                     // ret[b][t][h]
        float d = hnew - lbv;
        local_sse += d * d;
      }
    }

    // ---- two-level grid barrier (monotonic, agent scope) ----
    __syncthreads();
    if (tid == 0) {
      __threadfence();                 // release
      int old = __hip_atomic_fetch_add(gcnt, 1, __ATOMIC_RELAXED, __HIP_MEMORY_SCOPE_AGENT);
      if ((old & 31) == 31)            // last of this group's 32 arrivals this round
        __hip_atomic_fetch_add(root, 1, __ATOMIC_RELAXED, __HIP_MEMORY_SCOPE_AGENT);
      const int tgt = 8 * (ci + 1);
      while (__hip_atomic_load(root, __ATOMIC_RELAXED, __HIP_MEMORY_SCOPE_AGENT) < tgt)
        __builtin_amdgcn_s_sleep(1);
      __threadfence();                 // acquire
    }
    __syncthreads();
  }

  // ---------------- loss ----------------
  if (tid < 128) {
    float s = local_sse;
#pragma unroll
    for (int off = 32; off > 0; off >>= 1) s += __shfl_down(s, off);
    if (lane == 0) atomicAdd(sse, s);
  }
  __syncthreads();
  if (tid == 0) {
    __threadfence();
    int old = __hip_atomic_fetch_add(gcnt, 1, __ATOMIC_RELAXED, __HIP_MEMORY_SCOPE_AGENT);
    if ((old & 31) == 31)
      __hip_atomic_fetch_add(root, 1, __ATOMIC_RELAXED, __HIP_MEMORY_SCOPE_AGENT);
    while (__hip_atomic_load(root, __ATOMIC_RELAXED, __HIP_MEMORY_SCOPE_AGENT) < 8 * 33)
      __builtin_amdgcn_s_sleep(1);
    __threadfence();
  }
  __syncthreads();
  if (bid == 0 && tid == 0)
    out[524288] = __hip_atomic_load(sse, __ATOMIC_RELAXED, __HIP_MEMORY_SCOPE_AGENT)
                  * (1.0f / 524288.0f);
}

extern "C" void kernel_launch(void* const* d_in, const int* in_sizes, int n_in,
                              void* d_out, int out_size, void* d_ws, size_t ws_size,
                              hipStream_t stream) {
  (void)in_sizes; (void)n_in; (void)out_size; (void)ws_size;
  const float* x   = (const float*)d_in[0];
  const float* h0  = (const float*)d_in[1];
  const float* c0  = (const float*)d_in[2];
  const float* hm  = (const float*)d_in[3];
  const float* cm  = (const float*)d_in[4];
  const float* lb  = (const float*)d_in[5];
  const float* wih = (const float*)d_in[6];
  const float* whh = (const float*)d_in[7];
  const float* bi  = (const float*)d_in[8];
  const float* bh  = (const float*)d_in[9];
  float* out = (float*)d_out;
  unsigned char* ws = (unsigned char*)d_ws;

  static bool attr_done = false;
  if (!attr_done) {
    hipFuncSetAttribute((const void*)persist_kernel,
                        hipFuncAttributeMaxDynamicSharedMemorySize, DYN_LDS);
    attr_done = true;
  }

  prep_kernel<<<dim3(256), dim3(256), 0, stream>>>(x, h0, ws);
  persist_kernel<<<dim3(NBLK), dim3(NTHR), DYN_LDS, stream>>>(h0, c0, hm, cm, lb,
                                                              wih, whh, bi, bh, out, ws);
}